// Round 19
// baseline (24.729 us; speedup 1.0000x reference)
//
#include <hip/hip_runtime.h>
#include <hip/hip_bf16.h>
#include <math.h>

typedef __attribute__((ext_vector_type(8))) short short8;
typedef __attribute__((ext_vector_type(4))) float floatx4;

// ---- workspace layout (identical to R14/R17/R18) ----
#define TP_FCW   8192
#define TP_FC1   17408
#define TP_BIAS  24320
#define TP_N     24704
#define WS_WMAT  (1u << 20)  // 64*2048 bf16, MFMA-B-fragment layout

__device__ __forceinline__ float eluf(float v) {
  return v > 0.f ? v : __expf(v) - 1.f;
}

__device__ __forceinline__ unsigned short f2bf(float f) {
  __hip_bfloat16 h = __float2bfloat16(f);
  return *reinterpret_cast<unsigned short*>(&h);
}

// ============ prep: 197 blocks (identical to R14/R17/R18) ============
__global__ __launch_bounds__(256) void prep_kernel(
    const float* __restrict__ wm_di,
    const float* __restrict__ wm_ndi,
    const float* __restrict__ wm_dd,
    const float* __restrict__ b_di, const float* __restrict__ b_ndi,
    const float* __restrict__ b_dd,
    const float* __restrict__ fcw_di, const float* __restrict__ fcw_ndi,
    const float* __restrict__ fcw_dd,
    const float* __restrict__ fcb_di, const float* __restrict__ fcb_ndi,
    const float* __restrict__ fcb_dd,
    const float* __restrict__ fc1_w, const float* __restrict__ fc1_b,
    char* __restrict__ ws) {
  __shared__ float sm[64 * 65];
  const int t = threadIdx.x;
  float* wsf = (float*)ws;
  const int b = blockIdx.x;
  if (b < 128) {
    const int sel = b >> 6, h = b & 63;
    const float* w = (sel ? wm_dd : wm_di) + h * 4096;
#pragma unroll 4
    for (int i = 0; i < 16; ++i) {
      const int e = i * 256 + t;
      sm[(e >> 6) * 65 + (e & 63)] = w[e];
    }
    __syncthreads();
    if (t < 64) {
      float cs = 0.f, rs = 0.f;
#pragma unroll 8
      for (int I = 0; I < 64; ++I) {
        cs += sm[I * 65 + t];
        rs += sm[t * 65 + I];
      }
      wsf[sel * 4096 + t * 64 + h] = cs - rs;
    }
  } else if (b < 192) {
    const int h = b - 128;  // 0..63
    const float* w = wm_ndi + h * 4096;
#pragma unroll 4
    for (int i = 0; i < 16; ++i) {
      const int e = i * 256 + t;
      sm[(e >> 6) * 65 + (e & 63)] = w[e];
    }
    __syncthreads();
    const int kstep = t >> 2, kc = t & 3;
    const int lane = kc * 16 + (h & 15);
    const int n = h >> 4;
    short8 sv;
#pragma unroll
    for (int j = 0; j < 8; ++j) {
      const int k = kstep * 32 + kc * 8 + j;
      const int I = k >> 5, tt = k & 31;
      const int J = (I + 1 + tt) & 63;
      float v = 0.f;
      if (!(tt == 31 && I >= 32))
        v = 0.0625f * (sm[I * 65 + J] - sm[J * 65 + I]);
      sv[j] = (short)f2bf(v);
    }
    *(short8*)((__hip_bfloat16*)(ws + WS_WMAT) + (((n * 64 + kstep) * 64 + lane) << 3)) = sv;
  } else if (b < 195) {
    const int pick = b - 192;
    const float* src = (pick == 0) ? fcw_di : (pick == 1) ? fcw_ndi : fcw_dd;
    for (int i = t; i < 3072; i += 256) {
      const int e = i >> 6, hq = i & 63;
      wsf[TP_FCW + pick * 3072 + hq * 48 + e] = src[i];
    }
  } else if (b == 195) {
    for (int i = t; i < 6912; i += 256) {
      const int o = i / 144, k = i - o * 144;
      wsf[TP_FC1 + k * 48 + o] = fc1_w[i];
    }
  } else {
    for (int i = t; i < 384; i += 256) {
      float v;
      if (i < 64) v = b_di[i];
      else if (i < 128) v = b_ndi[i - 64];
      else if (i < 192) v = b_dd[i - 128];
      else if (i < 240) v = fcb_di[i - 192];
      else if (i < 288) v = fcb_ndi[i - 240];
      else if (i < 336) v = fcb_dd[i - 288];
      else v = fc1_b[i - 336];
      wsf[TP_BIAS + i] = v;
    }
  }
}

// ============ fused: grid 256, 1024 threads, BB=4, split-K tails ============
__global__ __launch_bounds__(1024, 4) void fused_kernel(
    const float* __restrict__ x,
    const float* __restrict__ fc2_w, const float* __restrict__ fc2_b,
    const char* __restrict__ ws,
    float* __restrict__ out) {
  __shared__ float xs[4][256];
  __shared__ __align__(16) unsigned short ldsA[4][2048];  // [row][k] bf16
  __shared__ float pxs[4][64], pds[4][64];
  __shared__ float hp[16][4][4][16];  // [kh][n][row][col]
  __shared__ float hh[3][4][64];
  __shared__ float emb_s[4][144];
  __shared__ float f1v_s[4][48];
  __shared__ __align__(16) float tp[TP_N];  // 96.5 KB tailpack

  const int t = threadIdx.x;
  const int b0 = blockIdx.x * 4;
  const short* __restrict__ wmaT = (const short*)(ws + WS_WMAT);
  const float4* __restrict__ ws4 = (const float4*)ws;
  float4* __restrict__ tp4 = (float4*)tp;

  xs[t >> 8][t & 255] = x[(b0 + (t >> 8)) * 256 + (t & 255)];
  __syncthreads();

  // ---- tailpack copy (coalesced; loads overlap rcp below) ----
#pragma unroll
  for (int j = 0; j < 7; ++j) {
    const int idx = t + j * 1024;
    if (idx < TP_N / 4) tp4[idx] = ws4[idx];
  }

  // ---- pooled x + telescoped pooled diff ----
  if (t < 256) {
    const int r = t >> 6, m = t & 63;
    const float* __restrict__ xr = xs[r];
    const int b4 = 4 * m;
    pxs[r][m] = 0.25f * (xr[b4] + xr[b4 + 1] + xr[b4 + 2] + xr[b4 + 3]);
    const int i3 = min(b4 + 4, 255), i4 = min(b4 + 5, 255);
    const float smv = 0.2f * (xr[b4 + 1] + xr[b4 + 2] + xr[b4 + 3] + xr[i3] + xr[i4]);
    float prev = __shfl_up(smv, 1, 64);
    if (m == 0) prev = xr[0];
    pds[r][m] = 0.25f * (smv - prev);
  }

  // ---- antisym rcp rectangle -> ldsA bf16 (single plane, 4 rcp/entry) ----
#pragma unroll
  for (int gi = 0; gi < 2; ++gi) {
    const int g = t + gi * 1024;       // 0..2047
    const int r = g >> 9;
    const int e0 = (g & 511) * 4;
    const int I = e0 >> 5;
    const float4 xiv = *(const float4*)&xs[r][I << 2];
    float ua[4], Ga[4];
    {
      const float ya[4] = {xiv.x, xiv.y, xiv.z, xiv.w};
#pragma unroll
      for (int a = 0; a < 4; ++a) {
        ua[a] = ya[a] + 1e-5f;
        Ga[a] = 2.f * ya[a] * ua[a];
      }
    }
#pragma unroll
    for (int i = 0; i < 4; ++i) {
      const int e = e0 + i;
      const int J = (I + 1 + (e & 31)) & 63;
      const float4 xjv = *(const float4*)&xs[r][J << 2];
      const float P01 = 2.f * xjv.x * xjv.y + (xjv.x + xjv.y) * 1e-5f;
      const float P23 = 2.f * xjv.z * xjv.w + (xjv.z + xjv.w) * 1e-5f;
      float s = 0.f;
#pragma unroll
      for (int ap = 0; ap < 2; ++ap) {
        const float u0 = ua[2 * ap], u1 = ua[2 * ap + 1];
        const float N01a = P01 - Ga[2 * ap], N01b = P01 - Ga[2 * ap + 1];
        const float N23a = P23 - Ga[2 * ap], N23b = P23 - Ga[2 * ap + 1];
        const float D01a = (xjv.x + u0) * (xjv.y + u0);
        const float D01b = (xjv.x + u1) * (xjv.y + u1);
        const float D23a = (xjv.z + u0) * (xjv.w + u0);
        const float D23b = (xjv.z + u1) * (xjv.w + u1);
        const float n01 = N01a * D01b + N01b * D01a;
        const float n23 = N23a * D23b + N23b * D23a;
        s += n01 * __builtin_amdgcn_rcpf(D01a * D01b);
        s += n23 * __builtin_amdgcn_rcpf(D23a * D23b);
      }
      ldsA[r][e] = f2bf(s);
    }
  }
  __syncthreads();

  // ---- MFMA einsum: s-outer, 4 N-accumulators, 16 MFMA/wave ----
  {
    const int kh = t >> 6, lane = t & 63;
    const int arow = (lane & 15) & 3;
    const int kofs = kh * 128 + ((lane >> 4) << 3);
    floatx4 acc0 = {0.f, 0.f, 0.f, 0.f}, acc1 = {0.f, 0.f, 0.f, 0.f};
    floatx4 acc2 = {0.f, 0.f, 0.f, 0.f}, acc3 = {0.f, 0.f, 0.f, 0.f};
#pragma unroll
    for (int s = 0; s < 4; ++s) {
      const int kk = kofs + s * 32;
      const short8 ah = *(const short8*)&ldsA[arow][kk];
      const int base = ((kh * 4 + s) * 64 + lane) << 3;  // n-stride 32768
      const short8 bv0 = *(const short8*)(wmaT + base);
      const short8 bv1 = *(const short8*)(wmaT + base + 32768);
      const short8 bv2 = *(const short8*)(wmaT + base + 65536);
      const short8 bv3 = *(const short8*)(wmaT + base + 98304);
      acc0 = __builtin_amdgcn_mfma_f32_16x16x32_bf16(ah, bv0, acc0, 0, 0, 0);
      acc1 = __builtin_amdgcn_mfma_f32_16x16x32_bf16(ah, bv1, acc1, 0, 0, 0);
      acc2 = __builtin_amdgcn_mfma_f32_16x16x32_bf16(ah, bv2, acc2, 0, 0, 0);
      acc3 = __builtin_amdgcn_mfma_f32_16x16x32_bf16(ah, bv3, acc3, 0, 0, 0);
    }
    // C/D (m89): col=lane&15, row=(lane>>4)*4+reg -> rows 0..3 = lanes<16, regs 0..3
    if (lane < 16) {
#pragma unroll
      for (int r = 0; r < 4; ++r) {
        hp[kh][0][r][lane] = acc0[r];
        hp[kh][1][r][lane] = acc1[r];
        hp[kh][2][r][lane] = acc2[r];
        hp[kh][3][r][lane] = acc3[r];
      }
    }
  }

  // ---- DI/DD projections: split-2 over ALL 1024 threads (same interval,
  //      balances the einsum waves; shfl_xor(1) combine) ----
  {
    const int half = t & 1;
    const int outp = t >> 1;        // 0..511
    const int type = outp >> 8;     // 0: di, 1: dd
    const int r = (outp >> 6) & 3;
    const int h = outp & 63;
    const float* __restrict__ pv = type ? pds[r] : pxs[r];
    const float* __restrict__ wt = tp + type * 4096;
    const int kb = half * 32;
    float a = 0.f;
#pragma unroll 8
    for (int j = 0; j < 32; ++j) {
      const int K = kb + j;
      a += pv[K] * wt[K * 64 + h];
    }
    a += __shfl_xor(a, 1, 64);
    if (half == 0) {
      const float bias = tp[TP_BIAS + (type ? 128 : 0) + h];
      hh[type ? 2 : 0][r][h] = eluf(a + bias);
    }
  }
  __syncthreads();

  // ---- combine K-slice partials -> NDI heads ----
  if (t < 256) {
    const int row = t >> 6, h = t & 63;
    const int n = h >> 4, c = h & 15;
    float v = tp[TP_BIAS + 64 + h];
#pragma unroll
    for (int kk = 0; kk < 16; ++kk) v += hp[kk][n][row][c];
    hh[1][row][h] = eluf(v);
  }
  __syncthreads();

  // ---- per-picker fc from LDS (transposed fcwT: [hq][e]) ----
  if (t < 4 * 144) {
    const int r = t / 144;
    const int k = t - r * 144;
    const int pick = k / 48;
    const int e = k - pick * 48;
    const float* __restrict__ fwt = tp + TP_FCW + pick * 3072;
    float a = tp[TP_BIAS + 192 + pick * 48 + e];
#pragma unroll 8
    for (int hq = 0; hq < 64; ++hq) a += hh[pick][r][hq] * fwt[hq * 48 + e];
    emb_s[r][k] = eluf(a);
  }
  __syncthreads();

  // ---- fc1: split-4 over 768 threads (36 iters + 2 shfl) ----
  if (t < 768) {
    const int q = t & 3;
    const int oidx = t >> 2;       // 0..191
    const int r = oidx / 48, o = oidx - r * 48;
    float a = 0.f;
#pragma unroll 6
    for (int j = 0; j < 36; ++j) {
      const int k = q * 36 + j;
      a += emb_s[r][k] * tp[TP_FC1 + k * 48 + o];
    }
    a += __shfl_xor(a, 1, 64);
    a += __shfl_xor(a, 2, 64);
    if (q == 0) f1v_s[r][o] = eluf(a + tp[TP_BIAS + 336 + o]);
  }
  __syncthreads();

  // ---- fc2: split-4 over 320 threads (12 iters + 2 shfl) ----
  if (t < 320) {
    const int q = t & 3;
    const int oidx = t >> 2;       // 0..79
    const int r = oidx / 20, o = oidx - r * 20;
    float a = 0.f;
#pragma unroll
    for (int j = 0; j < 12; ++j) {
      const int k = q * 12 + j;
      a += f1v_s[r][k] * fc2_w[o * 48 + k];
    }
    a += __shfl_xor(a, 1, 64);
    a += __shfl_xor(a, 2, 64);
    if (q == 0) out[(b0 + r) * 20 + o] = a + fc2_b[o];
  }
}

extern "C" void kernel_launch(void* const* d_in, const int* in_sizes, int n_in,
                              void* d_out, int out_size, void* d_ws, size_t ws_size,
                              hipStream_t stream) {
  const float* x       = (const float*)d_in[0];
  const float* wm_di   = (const float*)d_in[1];
  const float* b_di    = (const float*)d_in[2];
  const float* fcw_di  = (const float*)d_in[3];
  const float* fcb_di  = (const float*)d_in[4];
  const float* wm_ndi  = (const float*)d_in[5];
  const float* b_ndi   = (const float*)d_in[6];
  const float* fcw_ndi = (const float*)d_in[7];
  const float* fcb_ndi = (const float*)d_in[8];
  const float* wm_dd   = (const float*)d_in[9];
  const float* b_dd    = (const float*)d_in[10];
  const float* fcw_dd  = (const float*)d_in[11];
  const float* fcb_dd  = (const float*)d_in[12];
  const float* fc1_w   = (const float*)d_in[13];
  const float* fc1_b   = (const float*)d_in[14];
  const float* fc2_w   = (const float*)d_in[15];
  const float* fc2_b   = (const float*)d_in[16];
  float* out = (float*)d_out;
  char* ws = (char*)d_ws;

  prep_kernel<<<197, 256, 0, stream>>>(
      wm_di, wm_ndi, wm_dd, b_di, b_ndi, b_dd,
      fcw_di, fcw_ndi, fcw_dd, fcb_di, fcb_ndi, fcb_dd,
      fc1_w, fc1_b, ws);
  fused_kernel<<<256, 1024, 0, stream>>>(x, fc2_w, fc2_b, ws, out);
}

// Round 20
// 23.701 us; speedup vs baseline: 1.0433x; 1.0433x over previous
//
#include <hip/hip_runtime.h>
#include <hip/hip_bf16.h>
#include <math.h>

typedef __attribute__((ext_vector_type(8))) short short8;
typedef __attribute__((ext_vector_type(4))) float floatx4;
typedef __attribute__((ext_vector_type(2))) float f32x2;

// ---- workspace layout (identical to R14/R17/R18) ----
#define TP_FCW   8192
#define TP_FC1   17408
#define TP_BIAS  24320
#define TP_N     24704
#define WS_WMAT  (1u << 20)  // 64*2048 bf16, MFMA-B-fragment layout

__device__ __forceinline__ float eluf(float v) {
  return v > 0.f ? v : __expf(v) - 1.f;
}

__device__ __forceinline__ unsigned short f2bf(float f) {
  __hip_bfloat16 h = __float2bfloat16(f);
  return *reinterpret_cast<unsigned short*>(&h);
}

// ============ prep: 197 blocks (identical to R14/R17/R18) ============
__global__ __launch_bounds__(256) void prep_kernel(
    const float* __restrict__ wm_di,
    const float* __restrict__ wm_ndi,
    const float* __restrict__ wm_dd,
    const float* __restrict__ b_di, const float* __restrict__ b_ndi,
    const float* __restrict__ b_dd,
    const float* __restrict__ fcw_di, const float* __restrict__ fcw_ndi,
    const float* __restrict__ fcw_dd,
    const float* __restrict__ fcb_di, const float* __restrict__ fcb_ndi,
    const float* __restrict__ fcb_dd,
    const float* __restrict__ fc1_w, const float* __restrict__ fc1_b,
    char* __restrict__ ws) {
  __shared__ float sm[64 * 65];
  const int t = threadIdx.x;
  float* wsf = (float*)ws;
  const int b = blockIdx.x;
  if (b < 128) {
    const int sel = b >> 6, h = b & 63;
    const float* w = (sel ? wm_dd : wm_di) + h * 4096;
#pragma unroll 4
    for (int i = 0; i < 16; ++i) {
      const int e = i * 256 + t;
      sm[(e >> 6) * 65 + (e & 63)] = w[e];
    }
    __syncthreads();
    if (t < 64) {
      float cs = 0.f, rs = 0.f;
#pragma unroll 8
      for (int I = 0; I < 64; ++I) {
        cs += sm[I * 65 + t];
        rs += sm[t * 65 + I];
      }
      wsf[sel * 4096 + t * 64 + h] = cs - rs;
    }
  } else if (b < 192) {
    const int h = b - 128;  // 0..63
    const float* w = wm_ndi + h * 4096;
#pragma unroll 4
    for (int i = 0; i < 16; ++i) {
      const int e = i * 256 + t;
      sm[(e >> 6) * 65 + (e & 63)] = w[e];
    }
    __syncthreads();
    const int kstep = t >> 2, kc = t & 3;
    const int lane = kc * 16 + (h & 15);
    const int n = h >> 4;
    short8 sv;
#pragma unroll
    for (int j = 0; j < 8; ++j) {
      const int k = kstep * 32 + kc * 8 + j;
      const int I = k >> 5, tt = k & 31;
      const int J = (I + 1 + tt) & 63;
      float v = 0.f;
      if (!(tt == 31 && I >= 32))
        v = 0.0625f * (sm[I * 65 + J] - sm[J * 65 + I]);
      sv[j] = (short)f2bf(v);
    }
    *(short8*)((__hip_bfloat16*)(ws + WS_WMAT) + (((n * 64 + kstep) * 64 + lane) << 3)) = sv;
  } else if (b < 195) {
    const int pick = b - 192;
    const float* src = (pick == 0) ? fcw_di : (pick == 1) ? fcw_ndi : fcw_dd;
    for (int i = t; i < 3072; i += 256) {
      const int e = i >> 6, hq = i & 63;
      wsf[TP_FCW + pick * 3072 + hq * 48 + e] = src[i];
    }
  } else if (b == 195) {
    for (int i = t; i < 6912; i += 256) {
      const int o = i / 144, k = i - o * 144;
      wsf[TP_FC1 + k * 48 + o] = fc1_w[i];
    }
  } else {
    for (int i = t; i < 384; i += 256) {
      float v;
      if (i < 64) v = b_di[i];
      else if (i < 128) v = b_ndi[i - 64];
      else if (i < 192) v = b_dd[i - 128];
      else if (i < 240) v = fcb_di[i - 192];
      else if (i < 288) v = fcb_ndi[i - 240];
      else if (i < 336) v = fcb_dd[i - 288];
      else v = fc1_b[i - 336];
      wsf[TP_BIAS + i] = v;
    }
  }
}

// ============ fused: grid 256, 1024 threads, BB=4 (R18 structure, packed rcp) ============
__global__ __launch_bounds__(1024, 4) void fused_kernel(
    const float* __restrict__ x,
    const float* __restrict__ fc2_w, const float* __restrict__ fc2_b,
    const char* __restrict__ ws,
    float* __restrict__ out) {
  __shared__ float xs[4][256];
  __shared__ __align__(16) unsigned short ldsA[4][2048];  // [row][k] bf16
  __shared__ float pxs[4][64], pds[4][64];
  __shared__ float hp[16][4][4][16];  // [kh][n][row][col]
  __shared__ float hh[3][4][64];
  __shared__ float emb_s[4][144];
  __shared__ float f1v_s[4][48];
  __shared__ __align__(16) float tp[TP_N];  // 96.5 KB tailpack

  const int t = threadIdx.x;
  const int b0 = blockIdx.x * 4;
  const short* __restrict__ wmaT = (const short*)(ws + WS_WMAT);
  const float4* __restrict__ ws4 = (const float4*)ws;
  float4* __restrict__ tp4 = (float4*)tp;

  xs[t >> 8][t & 255] = x[(b0 + (t >> 8)) * 256 + (t & 255)];
  __syncthreads();

  // ---- tailpack copy (coalesced; loads overlap rcp below) ----
#pragma unroll
  for (int j = 0; j < 7; ++j) {
    const int idx = t + j * 1024;
    if (idx < TP_N / 4) tp4[idx] = ws4[idx];
  }

  // ---- pooled x + telescoped pooled diff ----
  if (t < 256) {
    const int r = t >> 6, m = t & 63;
    const float* __restrict__ xr = xs[r];
    const int b4 = 4 * m;
    pxs[r][m] = 0.25f * (xr[b4] + xr[b4 + 1] + xr[b4 + 2] + xr[b4 + 3]);
    const int i3 = min(b4 + 4, 255), i4 = min(b4 + 5, 255);
    const float smv = 0.2f * (xr[b4 + 1] + xr[b4 + 2] + xr[b4 + 3] + xr[i3] + xr[i4]);
    float prev = __shfl_up(smv, 1, 64);
    if (m == 0) prev = xr[0];
    pds[r][m] = 0.25f * (smv - prev);
  }

  // ---- antisym rcp rectangle -> ldsA bf16: packed f32x2 over the two c-pairs ----
  // Double-paired fractions (exact algebra, 4 rcp/entry); lanes {01,23} of
  // each f32x2 carry the two symmetric c-pairs -> v_pk_* on gfx950.
#pragma unroll
  for (int gi = 0; gi < 2; ++gi) {
    const int g = t + gi * 1024;       // 0..2047
    const int r = g >> 9;
    const int e0 = (g & 511) * 4;
    const int I = e0 >> 5;
    const float4 xiv = *(const float4*)&xs[r][I << 2];
    float ua[4], Ga[4];
    {
      const float ya[4] = {xiv.x, xiv.y, xiv.z, xiv.w};
#pragma unroll
      for (int a = 0; a < 4; ++a) {
        ua[a] = ya[a] + 1e-5f;
        Ga[a] = 2.f * ya[a] * ua[a];
      }
    }
#pragma unroll
    for (int i = 0; i < 4; ++i) {
      const int e = e0 + i;
      const int J = (I + 1 + (e & 31)) & 63;
      const float4 xjv = *(const float4*)&xs[r][J << 2];
      const f32x2 xl = {xjv.x, xjv.z};
      const f32x2 xh = {xjv.y, xjv.w};
      const f32x2 P = 2.f * xl * xh + (xl + xh) * 1e-5f;  // {P01, P23}
      f32x2 s2 = {0.f, 0.f};
#pragma unroll
      for (int ap = 0; ap < 2; ++ap) {
        const float u0 = ua[2 * ap], u1 = ua[2 * ap + 1];
        const f32x2 Da = (xl + u0) * (xh + u0);
        const f32x2 Db = (xl + u1) * (xh + u1);
        const f32x2 Na = P - Ga[2 * ap];
        const f32x2 Nb = P - Ga[2 * ap + 1];
        const f32x2 n = Na * Db + Nb * Da;
        const f32x2 d = Da * Db;
        f32x2 rr;
        rr.x = __builtin_amdgcn_rcpf(d.x);
        rr.y = __builtin_amdgcn_rcpf(d.y);
        s2 += n * rr;
      }
      ldsA[r][e] = f2bf(s2.x + s2.y);
    }
  }
  __syncthreads();

  // ---- MFMA einsum: s-outer, 4 N-accumulators, 16 MFMA/wave ----
  {
    const int kh = t >> 6, lane = t & 63;
    const int arow = (lane & 15) & 3;
    const int kofs = kh * 128 + ((lane >> 4) << 3);
    floatx4 acc0 = {0.f, 0.f, 0.f, 0.f}, acc1 = {0.f, 0.f, 0.f, 0.f};
    floatx4 acc2 = {0.f, 0.f, 0.f, 0.f}, acc3 = {0.f, 0.f, 0.f, 0.f};
#pragma unroll
    for (int s = 0; s < 4; ++s) {
      const int kk = kofs + s * 32;
      const short8 ah = *(const short8*)&ldsA[arow][kk];
      const int base = ((kh * 4 + s) * 64 + lane) << 3;  // n-stride 32768
      const short8 bv0 = *(const short8*)(wmaT + base);
      const short8 bv1 = *(const short8*)(wmaT + base + 32768);
      const short8 bv2 = *(const short8*)(wmaT + base + 65536);
      const short8 bv3 = *(const short8*)(wmaT + base + 98304);
      acc0 = __builtin_amdgcn_mfma_f32_16x16x32_bf16(ah, bv0, acc0, 0, 0, 0);
      acc1 = __builtin_amdgcn_mfma_f32_16x16x32_bf16(ah, bv1, acc1, 0, 0, 0);
      acc2 = __builtin_amdgcn_mfma_f32_16x16x32_bf16(ah, bv2, acc2, 0, 0, 0);
      acc3 = __builtin_amdgcn_mfma_f32_16x16x32_bf16(ah, bv3, acc3, 0, 0, 0);
    }
    // C/D (m89): col=lane&15, row=(lane>>4)*4+reg -> rows 0..3 = lanes<16, regs 0..3
    if (lane < 16) {
#pragma unroll
      for (int r = 0; r < 4; ++r) {
        hp[kh][0][r][lane] = acc0[r];
        hp[kh][1][r][lane] = acc1[r];
        hp[kh][2][r][lane] = acc2[r];
        hp[kh][3][r][lane] = acc3[r];
      }
    }
  }

  // ---- DI/DD projections from LDS tailpack (R18 form; same interval) ----
  if (t < 256) {
    const int r = t >> 6, h = t & 63;
    float adi = tp[TP_BIAS + h], add_ = tp[TP_BIAS + 128 + h];
#pragma unroll 8
    for (int K = 0; K < 64; ++K) {
      adi += pxs[r][K] * tp[K * 64 + h];
      add_ += pds[r][K] * tp[4096 + K * 64 + h];
    }
    hh[0][r][h] = eluf(adi);
    hh[2][r][h] = eluf(add_);
  }
  __syncthreads();

  // ---- combine K-slice partials -> NDI heads ----
  if (t < 256) {
    const int row = t >> 6, h = t & 63;
    const int n = h >> 4, c = h & 15;
    float v = tp[TP_BIAS + 64 + h];
#pragma unroll
    for (int kk = 0; kk < 16; ++kk) v += hp[kk][n][row][c];
    hh[1][row][h] = eluf(v);
  }
  __syncthreads();

  // ---- per-picker fc from LDS (transposed fcwT: [hq][e]) ----
  if (t < 4 * 144) {
    const int r = t / 144;
    const int k = t - r * 144;
    const int pick = k / 48;
    const int e = k - pick * 48;
    const float* __restrict__ fwt = tp + TP_FCW + pick * 3072;
    float a = tp[TP_BIAS + 192 + pick * 48 + e];
#pragma unroll 8
    for (int hq = 0; hq < 64; ++hq) a += hh[pick][r][hq] * fwt[hq * 48 + e];
    emb_s[r][k] = eluf(a);
  }
  __syncthreads();

  // ---- fc1 from LDS (transposed fc1T: [k][o]) ----
  if (t < 4 * 48) {
    const int r = t / 48, o = t - (t / 48) * 48;
    float a = tp[TP_BIAS + 336 + o];
#pragma unroll 8
    for (int k = 0; k < 144; ++k) a += emb_s[r][k] * tp[TP_FC1 + k * 48 + o];
    f1v_s[r][o] = eluf(a);
  }
  __syncthreads();

  // ---- fc2: 48 -> 20 ----
  if (t < 4 * 20) {
    const int r = t / 20, o = t - (t / 20) * 20;
    float a = fc2_b[o];
#pragma unroll
    for (int j = 0; j < 48; ++j) a += f1v_s[r][j] * fc2_w[o * 48 + j];
    out[(b0 + r) * 20 + o] = a;
  }
}

extern "C" void kernel_launch(void* const* d_in, const int* in_sizes, int n_in,
                              void* d_out, int out_size, void* d_ws, size_t ws_size,
                              hipStream_t stream) {
  const float* x       = (const float*)d_in[0];
  const float* wm_di   = (const float*)d_in[1];
  const float* b_di    = (const float*)d_in[2];
  const float* fcw_di  = (const float*)d_in[3];
  const float* fcb_di  = (const float*)d_in[4];
  const float* wm_ndi  = (const float*)d_in[5];
  const float* b_ndi   = (const float*)d_in[6];
  const float* fcw_ndi = (const float*)d_in[7];
  const float* fcb_ndi = (const float*)d_in[8];
  const float* wm_dd   = (const float*)d_in[9];
  const float* b_dd    = (const float*)d_in[10];
  const float* fcw_dd  = (const float*)d_in[11];
  const float* fcb_dd  = (const float*)d_in[12];
  const float* fc1_w   = (const float*)d_in[13];
  const float* fc1_b   = (const float*)d_in[14];
  const float* fc2_w   = (const float*)d_in[15];
  const float* fc2_b   = (const float*)d_in[16];
  float* out = (float*)d_out;
  char* ws = (char*)d_ws;

  prep_kernel<<<197, 256, 0, stream>>>(
      wm_di, wm_ndi, wm_dd, b_di, b_ndi, b_dd,
      fcw_di, fcw_ndi, fcw_dd, fcb_di, fcb_ndi, fcb_dd,
      fc1_w, fc1_b, ws);
  fused_kernel<<<256, 1024, 0, stream>>>(x, fc2_w, fc2_b, ws, out);
}